// Round 1
// baseline (4227.580 us; speedup 1.0000x reference)
//
#include <hip/hip_runtime.h>

#define CAPS_EPS 1e-8f

// ============================================================
// Layouts (all fp32):
//   h1T [512][20][20][256]   (b, y, x, c)  -- NHWC so conv2 A-loads coalesce on c
//   wT  [81*256][256]        (t*256+c, n)  -- permuted conv2 weights
//   h2T [512*36][256]        (m=b*36+p, c)
//   u   [512][1152*8]        (b, i*8+n)
//   uT  [1152*8][512]        (i*8+n, b)
//   b_log [1152*10][512]     (i*10+j, b)
//   smT [10*2][512]          (j*2+{max,1/Z}, b)
//   sT  [10*16][512]         (j*16+m, b)
//   v   [512][160]           (b, j*16+m)
//   vT  [10*16][512]
// ============================================================

// ---------- w2 [256][20736] -> wT[(t*256+c)][256], k_old = c*81+t ----------
__global__ __launch_bounds__(256) void k_wt(const float* __restrict__ w2,
                                            float* __restrict__ wT) {
    __shared__ float tile[64][65];   // [n][k_old]
    int k0 = blockIdx.x * 64;
    int n0 = blockIdx.y * 64;
    int tid = threadIdx.x;
    int nl = tid >> 4;             // 0..15
    int kl = (tid & 15) * 4;       // 0..60
#pragma unroll
    for (int q = 0; q < 4; ++q) {
        int n = nl + q * 16;
        float4 v = *reinterpret_cast<const float4*>(w2 + (size_t)(n0 + n) * 20736 + k0 + kl);
        tile[n][kl + 0] = v.x; tile[n][kl + 1] = v.y;
        tile[n][kl + 2] = v.z; tile[n][kl + 3] = v.w;
    }
    __syncthreads();
    int kl2 = tid >> 2;            // 0..63
    int nch = (tid & 3) * 16;      // 0..48
    int kold = k0 + kl2;
    int c = kold / 81;
    int tt = kold - c * 81;
    size_t know = (size_t)tt * 256 + c;
#pragma unroll
    for (int q = 0; q < 4; ++q) {
        float4 v = make_float4(tile[nch + q * 4 + 0][kl2], tile[nch + q * 4 + 1][kl2],
                               tile[nch + q * 4 + 2][kl2], tile[nch + q * 4 + 3][kl2]);
        *reinterpret_cast<float4*>(wT + know * 256 + n0 + nch + q * 4) = v;
    }
}

// ---------- conv1 + relu : x[512][28][28] -> h1T[b][y][x][c] ----------
__global__ __launch_bounds__(256) void k_conv1(const float* __restrict__ x,
                                               const float* __restrict__ w1,
                                               const float* __restrict__ b1,
                                               float* __restrict__ h1) {
    int blk = blockIdx.x;
    int b = blk / 5, strip = blk % 5;
    int y0 = strip * 4;
    int c = threadIdx.x;
    float w[81];
#pragma unroll
    for (int k = 0; k < 81; ++k) w[k] = w1[c * 81 + k];
    float bias = b1[c];
    const float* xb = x + (size_t)b * 784;
    for (int dy = 0; dy < 4; ++dy) {
        int y = y0 + dy;
        float acc[20];
#pragma unroll
        for (int i = 0; i < 20; ++i) acc[i] = bias;
#pragma unroll
        for (int ky = 0; ky < 9; ++ky) {
            float xr[28];
            const float4* xp = reinterpret_cast<const float4*>(xb + (y + ky) * 28);
#pragma unroll
            for (int q = 0; q < 7; ++q) {
                float4 v = xp[q];
                xr[q * 4 + 0] = v.x; xr[q * 4 + 1] = v.y;
                xr[q * 4 + 2] = v.z; xr[q * 4 + 3] = v.w;
            }
#pragma unroll
            for (int kx = 0; kx < 9; ++kx) {
                float wv = w[ky * 9 + kx];
#pragma unroll
                for (int xo = 0; xo < 20; ++xo)
                    acc[xo] = fmaf(xr[xo + kx], wv, acc[xo]);
            }
        }
#pragma unroll
        for (int xo = 0; xo < 20; ++xo)
            h1[((size_t)(b * 20 + y) * 20 + xo) * 256 + c] = fmaxf(acc[xo], 0.f);
    }
}

// ---------- h2 init with bias ----------
__global__ __launch_bounds__(256) void k_h2init(const float* __restrict__ b2,
                                                float* __restrict__ h2) {
    h2[(size_t)blockIdx.x * 256 + threadIdx.x] = b2[threadIdx.x];
}

// ---------- conv2 implicit GEMM: C[18432][256] += A(im2col h1T) * wT ----------
// grid (144 M-tiles, 2 N-tiles, 4 K-splits), 128x128 tile, BK=16, 8x8/thread.
__global__ __launch_bounds__(256) void k_conv2(const float* __restrict__ h1,
                                               const float* __restrict__ wT,
                                               float* __restrict__ h2) {
    __shared__ float At[16 * 128];
    __shared__ float Bt[16 * 128];
    int tid = threadIdx.x;
    int m0 = blockIdx.x * 128;
    int n0 = blockIdx.y * 128;
    int cbase = blockIdx.z * 64;

    // A-load mapping: 2 lanes per m (64B line per m per chunk)
    int mloc = tid >> 1;
    int half = tid & 1;
    {
    }
    int m = m0 + mloc;
    int mb = m / 36, mp = m % 36;
    int moy = mp / 6, mox = mp - moy * 6;
    const float* aptr0 = h1 + (size_t)mb * 102400 + moy * 2 * 5120 + mox * 2 * 256 + half * 8;

    // B-load mapping
    int kl = tid >> 4;             // 0..15
    int noff = (tid & 15) * 8;     // 0..120

    // compute mapping: wave quadrants, 8x8 lane grid -> 2-way-max LDS conflicts
    int wv = tid >> 6, lane = tid & 63;
    int row0 = ((wv >> 1) * 8 + (lane >> 3)) * 8;
    int col0 = ((wv & 1) * 8 + (lane & 7)) * 8;

    float acc[8][8];
#pragma unroll
    for (int r = 0; r < 8; ++r)
#pragma unroll
        for (int q = 0; q < 8; ++q) acc[r][q] = 0.f;

    float4 a0, a1, bv0, bv1;
    // prologue: step 0 (t=0, cc=0)
    {
        const float* ap = aptr0 + cbase;
        a0 = *reinterpret_cast<const float4*>(ap);
        a1 = *reinterpret_cast<const float4*>(ap + 4);
        const float* bp = wT + ((size_t)cbase + kl) * 256 + n0 + noff;
        bv0 = *reinterpret_cast<const float4*>(bp);
        bv1 = *reinterpret_cast<const float4*>(bp + 4);
    }
    for (int step = 0; step < 324; ++step) {
        __syncthreads();
        At[(half * 8 + 0) * 128 + mloc] = a0.x;
        At[(half * 8 + 1) * 128 + mloc] = a0.y;
        At[(half * 8 + 2) * 128 + mloc] = a0.z;
        At[(half * 8 + 3) * 128 + mloc] = a0.w;
        At[(half * 8 + 4) * 128 + mloc] = a1.x;
        At[(half * 8 + 5) * 128 + mloc] = a1.y;
        At[(half * 8 + 6) * 128 + mloc] = a1.z;
        At[(half * 8 + 7) * 128 + mloc] = a1.w;
        *reinterpret_cast<float4*>(&Bt[kl * 128 + noff]) = bv0;
        *reinterpret_cast<float4*>(&Bt[kl * 128 + noff + 4]) = bv1;
        __syncthreads();
        // prefetch next chunk (hidden under the 1024-FMA inner loop)
        if (step < 323) {
            int nxt = step + 1;
            int t = nxt >> 2;
            int cc = nxt & 3;
            int ky = t / 9, kx = t - ky * 9;
            int toff = ky * 5120 + kx * 256;
            int c0 = cbase + cc * 16;
            const float* ap = aptr0 + toff + c0;
            a0 = *reinterpret_cast<const float4*>(ap);
            a1 = *reinterpret_cast<const float4*>(ap + 4);
            const float* bp = wT + ((size_t)t * 256 + c0 + kl) * 256 + n0 + noff;
            bv0 = *reinterpret_cast<const float4*>(bp);
            bv1 = *reinterpret_cast<const float4*>(bp + 4);
        }
#pragma unroll
        for (int kk = 0; kk < 16; ++kk) {
            float4 aA = *reinterpret_cast<float4*>(&At[kk * 128 + row0]);
            float4 aB = *reinterpret_cast<float4*>(&At[kk * 128 + row0 + 4]);
            float4 bA = *reinterpret_cast<float4*>(&Bt[kk * 128 + col0]);
            float4 bB = *reinterpret_cast<float4*>(&Bt[kk * 128 + col0 + 4]);
            float ar[8] = {aA.x, aA.y, aA.z, aA.w, aB.x, aB.y, aB.z, aB.w};
            float br[8] = {bA.x, bA.y, bA.z, bA.w, bB.x, bB.y, bB.z, bB.w};
#pragma unroll
            for (int r = 0; r < 8; ++r)
#pragma unroll
                for (int q = 0; q < 8; ++q)
                    acc[r][q] = fmaf(ar[r], br[q], acc[r][q]);
        }
    }
#pragma unroll
    for (int r = 0; r < 8; ++r) {
        float* cp = h2 + (size_t)(m0 + row0 + r) * 256 + n0 + col0;
#pragma unroll
        for (int q = 0; q < 8; ++q) atomicAdd(cp + q, acc[r][q]);
    }
}

// ---------- squash over the 8-dim: h2T -> u[b][i*8+n] ----------
__global__ __launch_bounds__(256) void k_squash(const float* __restrict__ h2,
                                                float* __restrict__ u) {
    int idx = blockIdx.x * 256 + threadIdx.x;   // 589824 = 512*1152
    int g = idx & 31;
    int s = (idx >> 5) % 36;
    int b = idx / 1152;
    const float* hp = h2 + ((size_t)b * 36 + s) * 256 + g;
    float val[8];
    float s2 = 0.f;
#pragma unroll
    for (int n = 0; n < 8; ++n) {
        val[n] = hp[n * 32];
        s2 = fmaf(val[n], val[n], s2);
    }
    float scale = s2 / ((1.f + s2) * sqrtf(s2 + CAPS_EPS));
    float* up = u + ((size_t)b * 1152 + g * 36 + s) * 8;
#pragma unroll
    for (int n = 0; n < 8; ++n) up[n] = val[n] * scale;
}

// ---------- u[512][9216] -> uT[9216][512] ----------
__global__ __launch_bounds__(256) void k_utr(const float* __restrict__ u,
                                             float* __restrict__ uT) {
    __shared__ float tile[64][65];
    int c0 = blockIdx.x * 64;
    int b0 = blockIdx.y * 64;
    int tid = threadIdx.x;
    int rl = tid >> 4;
    int cl = (tid & 15) * 4;
#pragma unroll
    for (int q = 0; q < 4; ++q) {
        int r = rl + q * 16;
        float4 v = *reinterpret_cast<const float4*>(u + (size_t)(b0 + r) * 9216 + c0 + cl);
        tile[r][cl + 0] = v.x; tile[r][cl + 1] = v.y;
        tile[r][cl + 2] = v.z; tile[r][cl + 3] = v.w;
    }
    __syncthreads();
    int r2 = tid >> 2;
    int c2 = (tid & 3) * 16;
#pragma unroll
    for (int q = 0; q < 4; ++q) {
        float4 v = make_float4(tile[c2 + q * 4 + 0][r2], tile[c2 + q * 4 + 1][r2],
                               tile[c2 + q * 4 + 2][r2], tile[c2 + q * 4 + 3][r2]);
        *reinterpret_cast<float4*>(uT + (size_t)(c0 + r2) * 512 + b0 + c2 + q * 4) = v;
    }
}

// ---------- zero (float4 granularity) ----------
__global__ __launch_bounds__(256) void k_zero4(float* __restrict__ p) {
    reinterpret_cast<float4*>(p)[(size_t)blockIdx.x * 256 + threadIdx.x] = make_float4(0, 0, 0, 0);
}

// ---------- softmax stats over i (per b,j) + zero sT ----------
__global__ __launch_bounds__(256) void k_sm(const float* __restrict__ bl,
                                            float* __restrict__ smT,
                                            float* __restrict__ sT) {
    int j = blockIdx.x >> 1;
    int b = (blockIdx.x & 1) * 256 + threadIdx.x;
#pragma unroll
    for (int m = 0; m < 16; ++m) sT[(j * 16 + m) * 512 + b] = 0.f;
    const float* p = bl + j * 512 + b;
    float mx = -1e30f;
    for (int i = 0; i < 1152; ++i) mx = fmaxf(mx, p[(size_t)i * 5120]);
    float Z = 0.f;
    for (int i = 0; i < 1152; ++i) Z += expf(p[(size_t)i * 5120] - mx);
    smT[(j * 2 + 0) * 512 + b] = mx;
    smT[(j * 2 + 1) * 512 + b] = 1.f / Z;
}

// ---------- s[b,j,m] = sum_i c * (W u)  (atomics over i-tiles) ----------
__global__ __launch_bounds__(256) void k_s(const float* __restrict__ Wc,
                                           const float* __restrict__ uT,
                                           const float* __restrict__ bl,
                                           const float* __restrict__ smT,
                                           float* __restrict__ sT) {
    __shared__ float lw[8 * 1280];   // W[i0..i0+7][10][8][16]
    int tid = threadIdx.x;
    int i0 = blockIdx.x * 8;
    int b = blockIdx.y * 128 + (tid & 127);
    int mh = tid >> 7;               // wave-uniform
    const float* wg = Wc + (size_t)i0 * 1280;
#pragma unroll
    for (int r = 0; r < 10; ++r) {
        int q4 = (r * 256 + tid) * 4;
        *reinterpret_cast<float4*>(&lw[q4]) = *reinterpret_cast<const float4*>(wg + q4);
    }
    __syncthreads();
    float mjs[10], rzs[10];
#pragma unroll
    for (int j = 0; j < 10; ++j) {
        mjs[j] = smT[(j * 2 + 0) * 512 + b];
        rzs[j] = smT[(j * 2 + 1) * 512 + b];
    }
    float acc[80];
#pragma unroll
    for (int q = 0; q < 80; ++q) acc[q] = 0.f;
    for (int di = 0; di < 8; ++di) {
        int i = i0 + di;
        float ur[8];
#pragma unroll
        for (int n = 0; n < 8; ++n) ur[n] = uT[((size_t)i * 8 + n) * 512 + b];
#pragma unroll
        for (int j = 0; j < 10; ++j) {
            float c = expf(bl[((size_t)i * 10 + j) * 512 + b] - mjs[j]) * rzs[j];
            const float* wp = &lw[((di * 10 + j) * 8) * 16 + mh * 8];
#pragma unroll
            for (int mm = 0; mm < 8; ++mm) {
                float uh = 0.f;
#pragma unroll
                for (int n = 0; n < 8; ++n) uh = fmaf(wp[n * 16 + mm], ur[n], uh);
                acc[j * 8 + mm] = fmaf(c, uh, acc[j * 8 + mm]);
            }
        }
    }
#pragma unroll
    for (int j = 0; j < 10; ++j)
#pragma unroll
        for (int mm = 0; mm < 8; ++mm)
            atomicAdd(&sT[(j * 16 + mh * 8 + mm) * 512 + b], acc[j * 8 + mm]);
}

// ---------- v = squash(s); write v[b][160] and vT[160][b] ----------
__global__ __launch_bounds__(256) void k_v(const float* __restrict__ sT,
                                           float* __restrict__ v,
                                           float* __restrict__ vT) {
    int idx = blockIdx.x * 256 + threadIdx.x;   // 5120
    int j = idx >> 9;
    int b = idx & 511;
    float sv[16];
    float s2 = 0.f;
#pragma unroll
    for (int m = 0; m < 16; ++m) {
        sv[m] = sT[(j * 16 + m) * 512 + b];
        s2 = fmaf(sv[m], sv[m], s2);
    }
    float scale = s2 / ((1.f + s2) * sqrtf(s2 + CAPS_EPS));
#pragma unroll
    for (int m = 0; m < 16; ++m) {
        float val = sv[m] * scale;
        v[(size_t)b * 160 + j * 16 + m] = val;
        vT[(j * 16 + m) * 512 + b] = val;
    }
}

// ---------- b_log += sum_n u_n * (sum_m W v_m) ----------
__global__ __launch_bounds__(256) void k_bupd(const float* __restrict__ Wc,
                                              const float* __restrict__ uT,
                                              const float* __restrict__ vT,
                                              float* __restrict__ bl) {
    __shared__ float lw[8 * 1280];
    int tid = threadIdx.x;
    int i0 = blockIdx.x * 8;
    int b = blockIdx.y * 128 + (tid & 127);
    int ih = tid >> 7;               // wave-uniform
    const float* wg = Wc + (size_t)i0 * 1280;
#pragma unroll
    for (int r = 0; r < 10; ++r) {
        int q4 = (r * 256 + tid) * 4;
        *reinterpret_cast<float4*>(&lw[q4]) = *reinterpret_cast<const float4*>(wg + q4);
    }
    __syncthreads();
    float ur[4][8];
#pragma unroll
    for (int ii = 0; ii < 4; ++ii) {
        int i = i0 + ih * 4 + ii;
#pragma unroll
        for (int n = 0; n < 8; ++n) ur[ii][n] = uT[((size_t)i * 8 + n) * 512 + b];
    }
    for (int j = 0; j < 10; ++j) {
        float vj[16];
#pragma unroll
        for (int m = 0; m < 16; ++m) vj[m] = vT[(j * 16 + m) * 512 + b];
#pragma unroll
        for (int ii = 0; ii < 4; ++ii) {
            int di = ih * 4 + ii;
            const float* wp = &lw[((di * 10 + j) * 8) * 16];
            float t = 0.f;
#pragma unroll
            for (int n = 0; n < 8; ++n) {
                float wvv = 0.f;
#pragma unroll
                for (int m = 0; m < 16; ++m) wvv = fmaf(wp[n * 16 + m], vj[m], wvv);
                t = fmaf(ur[ii][n], wvv, t);
            }
            size_t idx = ((size_t)(i0 + di) * 10 + j) * 512 + b;
            bl[idx] += t;
        }
    }
}

// ---------- caps->out, pred->out, masked dec_in ----------
__global__ __launch_bounds__(256) void k_pred(const float* __restrict__ v,
                                              float* __restrict__ out,
                                              float* __restrict__ dec,
                                              int pred_off) {
    int b = blockIdx.x, t = threadIdx.x;
    __shared__ float sq[160];
    __shared__ float nrm[10];
    __shared__ int ip;
    float val = 0.f;
    if (t < 160) {
        val = v[(size_t)b * 160 + t];
        out[(size_t)b * 160 + t] = val;
        sq[t] = val * val;
    }
    __syncthreads();
    if (t < 10) {
        float s = 0.f;
#pragma unroll
        for (int k = 0; k < 16; ++k) s += sq[t * 16 + k];
        nrm[t] = s;
    }
    __syncthreads();
    if (t == 0) {
        float best = nrm[0];
        int bi = 0;
        for (int j = 1; j < 10; ++j)
            if (nrm[j] > best) { best = nrm[j]; bi = j; }   // first-max like jnp.argmax
        ip = bi;
        out[(size_t)pred_off + b] = (float)bi;
    }
    __syncthreads();
    if (t < 160) dec[(size_t)b * 160 + t] = ((t >> 4) == ip) ? val : 0.f;
}

// ---------- decoder GEMM: C[M,N] = act(A[M,K] @ B[K,N] + bias) ----------
template <int ACT>   // 0 = relu, 1 = sigmoid
__global__ __launch_bounds__(256) void k_gemm(const float* __restrict__ A,
                                              const float* __restrict__ B,
                                              const float* __restrict__ bias,
                                              float* __restrict__ C,
                                              int M, int K, int N) {
    __shared__ float As[16 * 64];
    __shared__ float Bs[16 * 64];
    int tid = threadIdx.x;
    int m0 = blockIdx.y * 64, n0 = blockIdx.x * 64;
    int arow = tid >> 2, akq = (tid & 3) * 4;
    int brow = tid >> 4, bcol = (tid & 15) * 4;
    int ty = tid >> 4, tx = tid & 15;
    float acc[4][4];
#pragma unroll
    for (int r = 0; r < 4; ++r)
#pragma unroll
        for (int q = 0; q < 4; ++q) acc[r][q] = 0.f;
    for (int k0 = 0; k0 < K; k0 += 16) {
        float4 av = *reinterpret_cast<const float4*>(A + (size_t)(m0 + arow) * K + k0 + akq);
        float4 bv = make_float4(0, 0, 0, 0);
        if (n0 + bcol < N)
            bv = *reinterpret_cast<const float4*>(B + (size_t)(k0 + brow) * N + n0 + bcol);
        __syncthreads();
        As[(akq + 0) * 64 + arow] = av.x;
        As[(akq + 1) * 64 + arow] = av.y;
        As[(akq + 2) * 64 + arow] = av.z;
        As[(akq + 3) * 64 + arow] = av.w;
        *reinterpret_cast<float4*>(&Bs[brow * 64 + bcol]) = bv;
        __syncthreads();
#pragma unroll
        for (int kk = 0; kk < 16; ++kk) {
            float4 a4 = *reinterpret_cast<float4*>(&As[kk * 64 + ty * 4]);
            float4 b4 = *reinterpret_cast<float4*>(&Bs[kk * 64 + tx * 4]);
            float ar[4] = {a4.x, a4.y, a4.z, a4.w};
            float br[4] = {b4.x, b4.y, b4.z, b4.w};
#pragma unroll
            for (int r = 0; r < 4; ++r)
#pragma unroll
                for (int q = 0; q < 4; ++q)
                    acc[r][q] = fmaf(ar[r], br[q], acc[r][q]);
        }
    }
#pragma unroll
    for (int r = 0; r < 4; ++r) {
        int mm = m0 + ty * 4 + r;
#pragma unroll
        for (int q = 0; q < 4; ++q) {
            int nn = n0 + tx * 4 + q;
            if (nn < N) {
                float val = acc[r][q] + bias[nn];
                if (ACT == 0) val = fmaxf(val, 0.f);
                else val = 1.f / (1.f + expf(-val));
                C[(size_t)mm * N + nn] = val;
            }
        }
    }
}

extern "C" void kernel_launch(void* const* d_in, const int* in_sizes, int n_in,
                              void* d_out, int out_size, void* d_ws, size_t ws_size,
                              hipStream_t stream) {
    const float* x   = (const float*)d_in[0];
    const float* w1  = (const float*)d_in[1];
    const float* b1  = (const float*)d_in[2];
    const float* w2  = (const float*)d_in[3];
    const float* b2  = (const float*)d_in[4];
    const float* Wc  = (const float*)d_in[5];
    const float* d1w = (const float*)d_in[6];
    const float* d1b = (const float*)d_in[7];
    const float* d2w = (const float*)d_in[8];
    const float* d2b = (const float*)d_in[9];
    const float* d3w = (const float*)d_in[10];
    const float* d3b = (const float*)d_in[11];
    float* out = (float*)d_out;
    float* ws  = (float*)d_ws;

    // workspace layout (floats). Peak = 62,455,808 f = 249.8 MB.
    float* wT = ws;                        // 5,308,416
    float* h1 = ws + 5308416;              // 52,428,800
    float* h2 = h1 + 52428800;             // 4,718,592
    // everything below aliases h1 (dead after conv2):
    float* u   = h1;                       // 4,718,592
    float* uT  = u + 4718592;              // 4,718,592
    float* bl  = uT + 4718592;             // 5,898,240
    float* smT = bl + 5898240;             // 10,240
    float* sT  = smT + 10240;              // 81,920
    float* v   = sT + 81920;               // 81,920
    float* vT  = v + 81920;                // 81,920
    float* dec = vT + 81920;               // 81,920
    float* r1  = dec + 81920;              // 262,144
    float* r2  = r1 + 262144;              // 524,288

    int pred_off = out_size - 512;         // caps(81920) + recon(401408)

    k_wt<<<dim3(324, 4), 256, 0, stream>>>(w2, wT);
    k_conv1<<<2560, 256, 0, stream>>>(x, w1, b1, h1);
    k_h2init<<<18432, 256, 0, stream>>>(b2, h2);
    k_conv2<<<dim3(144, 2, 4), 256, 0, stream>>>(h1, wT, h2);
    k_squash<<<2304, 256, 0, stream>>>(h2, u);
    k_utr<<<dim3(144, 8), 256, 0, stream>>>(u, uT);
    k_zero4<<<5760, 256, 0, stream>>>(bl);   // 5,898,240 floats

    for (int it = 0; it < 3; ++it) {
        k_sm<<<20, 256, 0, stream>>>(bl, smT, sT);
        k_s<<<dim3(144, 4), 256, 0, stream>>>(Wc, uT, bl, smT, sT);
        k_v<<<20, 256, 0, stream>>>(sT, v, vT);
        if (it < 2) k_bupd<<<dim3(144, 4), 256, 0, stream>>>(Wc, uT, vT, bl);
    }

    k_pred<<<512, 256, 0, stream>>>(v, out, dec, pred_off);
    k_gemm<0><<<dim3(8, 8), 256, 0, stream>>>(dec, d1w, d1b, r1, 512, 160, 512);
    k_gemm<0><<<dim3(16, 8), 256, 0, stream>>>(r1, d2w, d2b, r2, 512, 512, 1024);
    k_gemm<1><<<dim3(13, 8), 256, 0, stream>>>(r2, d3w, d3b, out + 81920, 512, 1024, 784);
}

// Round 2
// 1784.552 us; speedup vs baseline: 2.3690x; 2.3690x over previous
//
#include <hip/hip_runtime.h>

#define CAPS_EPS 1e-8f

typedef __attribute__((ext_vector_type(8))) short short8;
typedef __attribute__((ext_vector_type(4))) float f32x4;

__device__ inline ushort bf16_rn(float f) {
    uint u = __float_as_uint(f);
    u += 0x7fff + ((u >> 16) & 1);
    return (ushort)(u >> 16);
}
__device__ inline float bf16_f(ushort h) { return __uint_as_float((uint)h << 16); }

// ============================================================
// Layouts:
//   h1hi/h1lo [512][20][20][256] bf16 (NHWC) -- conv1 out, split
//   wBhi/wBlo [256][20736] bf16, k = (ky*9+kx)*256 + c
//   h2  [512*36][256] fp32
//   u   [512][1152*8], uT [9216][512]
//   bl  [1152*10][512], Z [10][512], sT [160][512], v [512][160], vT [160][512]
// ============================================================

// ---------- w2 [256][256*81] -> wB[n][t*256+c] hi/lo ----------
__global__ __launch_bounds__(256) void k_wt2(const float* __restrict__ w2,
                                             ushort* __restrict__ wBhi,
                                             ushort* __restrict__ wBlo) {
    int n = blockIdx.x;
    int c = threadIdx.x;
    const float* src = w2 + (size_t)n * 20736 + c * 81;
    ushort* dh = wBhi + (size_t)n * 20736 + c;
    ushort* dl = wBlo + (size_t)n * 20736 + c;
    for (int t = 0; t < 81; ++t) {
        float f = src[t];
        ushort hi = bf16_rn(f);
        ushort lo = bf16_rn(f - bf16_f(hi));
        dh[t * 256] = hi;
        dl[t * 256] = lo;
    }
}

// ---------- conv1 + relu -> bf16 split NHWC ----------
__global__ __launch_bounds__(256) void k_conv1(const float* __restrict__ x,
                                               const float* __restrict__ w1,
                                               const float* __restrict__ b1,
                                               ushort* __restrict__ h1hi,
                                               ushort* __restrict__ h1lo) {
    int blk = blockIdx.x;
    int b = blk / 5, strip = blk % 5;
    int y0 = strip * 4;
    int c = threadIdx.x;
    float w[81];
#pragma unroll
    for (int k = 0; k < 81; ++k) w[k] = w1[c * 81 + k];
    float bias = b1[c];
    const float* xb = x + (size_t)b * 784;
    for (int dy = 0; dy < 4; ++dy) {
        int y = y0 + dy;
        float acc[20];
#pragma unroll
        for (int i = 0; i < 20; ++i) acc[i] = bias;
#pragma unroll
        for (int ky = 0; ky < 9; ++ky) {
            float xr[28];
            const float4* xp = reinterpret_cast<const float4*>(xb + (y + ky) * 28);
#pragma unroll
            for (int q = 0; q < 7; ++q) {
                float4 v = xp[q];
                xr[q * 4 + 0] = v.x; xr[q * 4 + 1] = v.y;
                xr[q * 4 + 2] = v.z; xr[q * 4 + 3] = v.w;
            }
#pragma unroll
            for (int kx = 0; kx < 9; ++kx) {
                float wv = w[ky * 9 + kx];
#pragma unroll
                for (int xo = 0; xo < 20; ++xo)
                    acc[xo] = fmaf(xr[xo + kx], wv, acc[xo]);
            }
        }
#pragma unroll
        for (int xo = 0; xo < 20; ++xo) {
            float a = fmaxf(acc[xo], 0.f);
            ushort hi = bf16_rn(a);
            ushort lo = bf16_rn(a - bf16_f(hi));
            size_t o = ((size_t)(b * 20 + y) * 20 + xo) * 256 + c;
            h1hi[o] = hi;
            h1lo[o] = lo;
        }
    }
}

// ---------- h2 init with bias ----------
__global__ __launch_bounds__(256) void k_h2init(const float* __restrict__ b2,
                                                float* __restrict__ h2) {
    h2[(size_t)blockIdx.x * 256 + threadIdx.x] = b2[threadIdx.x];
}

// ---------- conv2: split-bf16 MFMA implicit GEMM ----------
// C[18432][256] += A(im2col h1) * B.  128x128 tile, BK=32, K-split 2.
// 3-term split: hi*hi + hi*lo + lo*hi.
__global__ __launch_bounds__(256) void k_conv2m(const ushort* __restrict__ h1hi,
                                                const ushort* __restrict__ h1lo,
                                                const ushort* __restrict__ wBhi,
                                                const ushort* __restrict__ wBlo,
                                                float* __restrict__ h2) {
    __shared__ ushort Ahi[128 * 32];
    __shared__ ushort Alo[128 * 32];
    __shared__ ushort Bhi[128 * 32];
    __shared__ ushort Blo[128 * 32];
    int tid = threadIdx.x;
    int m0 = blockIdx.x * 128;
    int n0 = blockIdx.y * 128;
    int kbase = blockIdx.z * 10368;

    // staging mapping: 2 threads per row, 32B (16 bf16) each
    int mloc = tid >> 1, half = tid & 1;
    int hoff = half * 16;
    int m = m0 + mloc;
    int mb = m / 36, mp = m - mb * 36;
    int oy = mp / 6, ox = mp - oy * 6;
    const size_t abase = ((size_t)mb * 400 + oy * 40 + ox * 2) * 256;
    const size_t bbase = (size_t)(n0 + mloc) * 20736;

    // frag mapping
    int wv = tid >> 6, lane = tid & 63;
    int mhalf = (wv >> 1) * 64, nhalf = (wv & 1) * 64;
    int lrow = lane & 15, quad = lane >> 4;

    f32x4 acc[4][4];
#pragma unroll
    for (int a = 0; a < 4; ++a)
#pragma unroll
        for (int bq = 0; bq < 4; ++bq) acc[a][bq] = (f32x4){0.f, 0.f, 0.f, 0.f};

    float4 pa0, pa1, pl0, pl1, pb0, pb1, pq0, pq1;
#define LOADCHUNK(KS)                                                              \
    {                                                                              \
        int k = kbase + (KS) * 32;                                                 \
        int t = k >> 8, c = k & 255;                                               \
        int ky = t / 9, kx = t - ky * 9;                                           \
        const ushort* ap = h1hi + abase + ky * 5120 + kx * 256 + c + hoff;         \
        const ushort* al = h1lo + abase + ky * 5120 + kx * 256 + c + hoff;         \
        pa0 = *reinterpret_cast<const float4*>(ap);                                \
        pa1 = *reinterpret_cast<const float4*>(ap + 8);                            \
        pl0 = *reinterpret_cast<const float4*>(al);                                \
        pl1 = *reinterpret_cast<const float4*>(al + 8);                            \
        const ushort* bp = wBhi + bbase + k + hoff;                                \
        const ushort* bq2 = wBlo + bbase + k + hoff;                               \
        pb0 = *reinterpret_cast<const float4*>(bp);                                \
        pb1 = *reinterpret_cast<const float4*>(bp + 8);                            \
        pq0 = *reinterpret_cast<const float4*>(bq2);                               \
        pq1 = *reinterpret_cast<const float4*>(bq2 + 8);                           \
    }

    LOADCHUNK(0);
    for (int ks = 0; ks < 324; ++ks) {
        __syncthreads();
        *reinterpret_cast<float4*>(&Ahi[mloc * 32 + hoff]) = pa0;
        *reinterpret_cast<float4*>(&Ahi[mloc * 32 + hoff + 8]) = pa1;
        *reinterpret_cast<float4*>(&Alo[mloc * 32 + hoff]) = pl0;
        *reinterpret_cast<float4*>(&Alo[mloc * 32 + hoff + 8]) = pl1;
        *reinterpret_cast<float4*>(&Bhi[mloc * 32 + hoff]) = pb0;
        *reinterpret_cast<float4*>(&Bhi[mloc * 32 + hoff + 8]) = pb1;
        *reinterpret_cast<float4*>(&Blo[mloc * 32 + hoff]) = pq0;
        *reinterpret_cast<float4*>(&Blo[mloc * 32 + hoff + 8]) = pq1;
        __syncthreads();
        if (ks < 323) LOADCHUNK(ks + 1);

        short8 bh[4], blo[4];
#pragma unroll
        for (int tn = 0; tn < 4; ++tn) {
            int off = (nhalf + tn * 16 + lrow) * 32 + quad * 8;
            bh[tn] = *reinterpret_cast<short8*>(&Bhi[off]);
            blo[tn] = *reinterpret_cast<short8*>(&Blo[off]);
        }
#pragma unroll
        for (int tm = 0; tm < 4; ++tm) {
            int off = (mhalf + tm * 16 + lrow) * 32 + quad * 8;
            short8 ah = *reinterpret_cast<short8*>(&Ahi[off]);
            short8 al = *reinterpret_cast<short8*>(&Alo[off]);
#pragma unroll
            for (int tn = 0; tn < 4; ++tn) {
                acc[tm][tn] = __builtin_amdgcn_mfma_f32_16x16x32_bf16(ah, bh[tn], acc[tm][tn], 0, 0, 0);
                acc[tm][tn] = __builtin_amdgcn_mfma_f32_16x16x32_bf16(ah, blo[tn], acc[tm][tn], 0, 0, 0);
                acc[tm][tn] = __builtin_amdgcn_mfma_f32_16x16x32_bf16(al, bh[tn], acc[tm][tn], 0, 0, 0);
            }
        }
    }
#undef LOADCHUNK

#pragma unroll
    for (int tm = 0; tm < 4; ++tm) {
        int mrow = m0 + mhalf + tm * 16 + quad * 4;
#pragma unroll
        for (int tn = 0; tn < 4; ++tn) {
            int ncol = n0 + nhalf + tn * 16 + lrow;
#pragma unroll
            for (int r = 0; r < 4; ++r)
                atomicAdd(&h2[(size_t)(mrow + r) * 256 + ncol], acc[tm][tn][r]);
        }
    }
}

// ---------- squash over 8-dim: h2 -> u[b][i*8+n] ----------
__global__ __launch_bounds__(256) void k_squash(const float* __restrict__ h2,
                                                float* __restrict__ u) {
    int idx = blockIdx.x * 256 + threadIdx.x;
    int g = idx & 31;
    int s = (idx >> 5) % 36;
    int b = idx / 1152;
    const float* hp = h2 + ((size_t)b * 36 + s) * 256 + g;
    float val[8];
    float s2 = 0.f;
#pragma unroll
    for (int n = 0; n < 8; ++n) {
        val[n] = hp[n * 32];
        s2 = fmaf(val[n], val[n], s2);
    }
    float scale = s2 / ((1.f + s2) * sqrtf(s2 + CAPS_EPS));
    float* up = u + ((size_t)b * 1152 + g * 36 + s) * 8;
#pragma unroll
    for (int n = 0; n < 8; ++n) up[n] = val[n] * scale;
}

// ---------- u[512][9216] -> uT[9216][512] ----------
__global__ __launch_bounds__(256) void k_utr(const float* __restrict__ u,
                                             float* __restrict__ uT) {
    __shared__ float tile[64][65];
    int c0 = blockIdx.x * 64;
    int b0 = blockIdx.y * 64;
    int tid = threadIdx.x;
    int rl = tid >> 4;
    int cl = (tid & 15) * 4;
#pragma unroll
    for (int q = 0; q < 4; ++q) {
        int r = rl + q * 16;
        float4 v = *reinterpret_cast<const float4*>(u + (size_t)(b0 + r) * 9216 + c0 + cl);
        tile[r][cl + 0] = v.x; tile[r][cl + 1] = v.y;
        tile[r][cl + 2] = v.z; tile[r][cl + 3] = v.w;
    }
    __syncthreads();
    int r2 = tid >> 2;
    int c2 = (tid & 3) * 16;
#pragma unroll
    for (int q = 0; q < 4; ++q) {
        float4 v = make_float4(tile[c2 + q * 4 + 0][r2], tile[c2 + q * 4 + 1][r2],
                               tile[c2 + q * 4 + 2][r2], tile[c2 + q * 4 + 3][r2]);
        *reinterpret_cast<float4*>(uT + (size_t)(c0 + r2) * 512 + b0 + c2 + q * 4) = v;
    }
}

// ---------- zero (float4 granularity) ----------
__global__ __launch_bounds__(256) void k_zero4(float* __restrict__ p) {
    reinterpret_cast<float4*>(p)[(size_t)blockIdx.x * 256 + threadIdx.x] = make_float4(0, 0, 0, 0);
}

// ---------- s[b,j,m] = sum_i c * (W u), c from exp(bl)/Z (or uniform it0) ----------
__global__ __launch_bounds__(256) void k_s(const float* __restrict__ Wc,
                                           const float* __restrict__ uT,
                                           const float* __restrict__ bl,
                                           const float* __restrict__ Z,
                                           float* __restrict__ sT,
                                           int first) {
    __shared__ float lw[8 * 1280];
    int tid = threadIdx.x;
    int i0 = blockIdx.x * 8;
    int b = blockIdx.y * 128 + (tid & 127);
    int mh = tid >> 7;
    const float* wg = Wc + (size_t)i0 * 1280;
#pragma unroll
    for (int r = 0; r < 10; ++r) {
        int q4 = (r * 256 + tid) * 4;
        *reinterpret_cast<float4*>(&lw[q4]) = *reinterpret_cast<const float4*>(wg + q4);
    }
    __syncthreads();
    float rzs[10];
    if (!first) {
#pragma unroll
        for (int j = 0; j < 10; ++j) rzs[j] = 1.0f / Z[j * 512 + b];
    }
    float acc[80];
#pragma unroll
    for (int q = 0; q < 80; ++q) acc[q] = 0.f;
    for (int di = 0; di < 8; ++di) {
        int i = i0 + di;
        float ur[8];
#pragma unroll
        for (int n = 0; n < 8; ++n) ur[n] = uT[((size_t)i * 8 + n) * 512 + b];
#pragma unroll
        for (int j = 0; j < 10; ++j) {
            float c;
            if (first) c = (1.0f / 1152.0f);
            else c = expf(bl[((size_t)i * 10 + j) * 512 + b]) * rzs[j];
            const float* wp = &lw[((di * 10 + j) * 8) * 16 + mh * 8];
#pragma unroll
            for (int mm = 0; mm < 8; ++mm) {
                float uh = 0.f;
#pragma unroll
                for (int n = 0; n < 8; ++n) uh = fmaf(wp[n * 16 + mm], ur[n], uh);
                acc[j * 8 + mm] = fmaf(c, uh, acc[j * 8 + mm]);
            }
        }
    }
#pragma unroll
    for (int j = 0; j < 10; ++j)
#pragma unroll
        for (int mm = 0; mm < 8; ++mm)
            atomicAdd(&sT[(j * 16 + mh * 8 + mm) * 512 + b], acc[j * 8 + mm]);
}

// ---------- v = squash(s); write v, vT; zero sT and Z for next round ----------
__global__ __launch_bounds__(256) void k_v(const float* __restrict__ sT,
                                           float* __restrict__ v,
                                           float* __restrict__ vT,
                                           float* __restrict__ sTz,
                                           float* __restrict__ Z) {
    int idx = blockIdx.x * 256 + threadIdx.x;   // 5120
    int j = idx >> 9;
    int b = idx & 511;
    float sv[16];
    float s2 = 0.f;
#pragma unroll
    for (int m = 0; m < 16; ++m) {
        sv[m] = sT[(j * 16 + m) * 512 + b];
        s2 = fmaf(sv[m], sv[m], s2);
    }
    float scale = s2 / ((1.f + s2) * sqrtf(s2 + CAPS_EPS));
#pragma unroll
    for (int m = 0; m < 16; ++m) {
        float val = sv[m] * scale;
        v[(size_t)b * 160 + j * 16 + m] = val;
        vT[(j * 16 + m) * 512 + b] = val;
        sTz[(j * 16 + m) * 512 + b] = 0.f;
    }
    Z[idx] = 0.f;
}

// ---------- b_log += u . (W v); accumulate Z = sum_i exp(b_log_new) ----------
__global__ __launch_bounds__(256) void k_bupd(const float* __restrict__ Wc,
                                              const float* __restrict__ uT,
                                              const float* __restrict__ vT,
                                              float* __restrict__ bl,
                                              float* __restrict__ Z) {
    __shared__ float lw[8 * 1280];
    int tid = threadIdx.x;
    int i0 = blockIdx.x * 8;
    int b = blockIdx.y * 128 + (tid & 127);
    int ih = tid >> 7;
    const float* wg = Wc + (size_t)i0 * 1280;
#pragma unroll
    for (int r = 0; r < 10; ++r) {
        int q4 = (r * 256 + tid) * 4;
        *reinterpret_cast<float4*>(&lw[q4]) = *reinterpret_cast<const float4*>(wg + q4);
    }
    __syncthreads();
    float ur[4][8];
#pragma unroll
    for (int ii = 0; ii < 4; ++ii) {
        int i = i0 + ih * 4 + ii;
#pragma unroll
        for (int n = 0; n < 8; ++n) ur[ii][n] = uT[((size_t)i * 8 + n) * 512 + b];
    }
    for (int j = 0; j < 10; ++j) {
        float vj[16];
#pragma unroll
        for (int m = 0; m < 16; ++m) vj[m] = vT[(j * 16 + m) * 512 + b];
        float zp = 0.f;
#pragma unroll
        for (int ii = 0; ii < 4; ++ii) {
            int di = ih * 4 + ii;
            const float* wp = &lw[((di * 10 + j) * 8) * 16];
            float t = 0.f;
#pragma unroll
            for (int n = 0; n < 8; ++n) {
                float wvv = 0.f;
#pragma unroll
                for (int m = 0; m < 16; ++m) wvv = fmaf(wp[n * 16 + m], vj[m], wvv);
                t = fmaf(ur[ii][n], wvv, t);
            }
            size_t idx = ((size_t)(i0 + di) * 10 + j) * 512 + b;
            float nb = bl[idx] + t;
            bl[idx] = nb;
            zp += expf(nb);
        }
        atomicAdd(&Z[j * 512 + b], zp);
    }
}

// ---------- caps->out, pred->out, masked dec_in ----------
__global__ __launch_bounds__(256) void k_pred(const float* __restrict__ v,
                                              float* __restrict__ out,
                                              float* __restrict__ dec,
                                              int pred_off) {
    int b = blockIdx.x, t = threadIdx.x;
    __shared__ float sq[160];
    __shared__ float nrm[10];
    __shared__ int ip;
    float val = 0.f;
    if (t < 160) {
        val = v[(size_t)b * 160 + t];
        out[(size_t)b * 160 + t] = val;
        sq[t] = val * val;
    }
    __syncthreads();
    if (t < 10) {
        float s = 0.f;
#pragma unroll
        for (int k = 0; k < 16; ++k) s += sq[t * 16 + k];
        nrm[t] = s;
    }
    __syncthreads();
    if (t == 0) {
        float best = nrm[0];
        int bi = 0;
        for (int j = 1; j < 10; ++j)
            if (nrm[j] > best) { best = nrm[j]; bi = j; }
        ip = bi;
        out[(size_t)pred_off + b] = (float)bi;
    }
    __syncthreads();
    if (t < 160) dec[(size_t)b * 160 + t] = ((t >> 4) == ip) ? val : 0.f;
}

// ---------- decoder GEMM ----------
template <int ACT>
__global__ __launch_bounds__(256) void k_gemm(const float* __restrict__ A,
                                              const float* __restrict__ B,
                                              const float* __restrict__ bias,
                                              float* __restrict__ C,
                                              int M, int K, int N) {
    __shared__ float As[16 * 64];
    __shared__ float Bs[16 * 64];
    int tid = threadIdx.x;
    int m0 = blockIdx.y * 64, n0 = blockIdx.x * 64;
    int arow = tid >> 2, akq = (tid & 3) * 4;
    int brow = tid >> 4, bcol = (tid & 15) * 4;
    int ty = tid >> 4, tx = tid & 15;
    float acc[4][4];
#pragma unroll
    for (int r = 0; r < 4; ++r)
#pragma unroll
        for (int q = 0; q < 4; ++q) acc[r][q] = 0.f;
    for (int k0 = 0; k0 < K; k0 += 16) {
        float4 av = *reinterpret_cast<const float4*>(A + (size_t)(m0 + arow) * K + k0 + akq);
        float4 bv = make_float4(0, 0, 0, 0);
        if (n0 + bcol < N)
            bv = *reinterpret_cast<const float4*>(B + (size_t)(k0 + brow) * N + n0 + bcol);
        __syncthreads();
        As[(akq + 0) * 64 + arow] = av.x;
        As[(akq + 1) * 64 + arow] = av.y;
        As[(akq + 2) * 64 + arow] = av.z;
        As[(akq + 3) * 64 + arow] = av.w;
        *reinterpret_cast<float4*>(&Bs[brow * 64 + bcol]) = bv;
        __syncthreads();
#pragma unroll
        for (int kk = 0; kk < 16; ++kk) {
            float4 a4 = *reinterpret_cast<float4*>(&As[kk * 64 + ty * 4]);
            float4 b4 = *reinterpret_cast<float4*>(&Bs[kk * 64 + tx * 4]);
            float ar[4] = {a4.x, a4.y, a4.z, a4.w};
            float br[4] = {b4.x, b4.y, b4.z, b4.w};
#pragma unroll
            for (int r = 0; r < 4; ++r)
#pragma unroll
                for (int q = 0; q < 4; ++q)
                    acc[r][q] = fmaf(ar[r], br[q], acc[r][q]);
        }
    }
#pragma unroll
    for (int r = 0; r < 4; ++r) {
        int mm = m0 + ty * 4 + r;
#pragma unroll
        for (int q = 0; q < 4; ++q) {
            int nn = n0 + tx * 4 + q;
            if (nn < N) {
                float val = acc[r][q] + bias[nn];
                if (ACT == 0) val = fmaxf(val, 0.f);
                else val = 1.f / (1.f + expf(-val));
                C[(size_t)mm * N + nn] = val;
            }
        }
    }
}

extern "C" void kernel_launch(void* const* d_in, const int* in_sizes, int n_in,
                              void* d_out, int out_size, void* d_ws, size_t ws_size,
                              hipStream_t stream) {
    const float* x   = (const float*)d_in[0];
    const float* w1  = (const float*)d_in[1];
    const float* b1  = (const float*)d_in[2];
    const float* w2  = (const float*)d_in[3];
    const float* b2  = (const float*)d_in[4];
    const float* Wc  = (const float*)d_in[5];
    const float* d1w = (const float*)d_in[6];
    const float* d1b = (const float*)d_in[7];
    const float* d2w = (const float*)d_in[8];
    const float* d2b = (const float*)d_in[9];
    const float* d3w = (const float*)d_in[10];
    const float* d3b = (const float*)d_in[11];
    float* out = (float*)d_out;

    // ---- workspace (bytes): wB 21,233,664 | h1 209,715,200 | h2 18,874,368 = 249,823,232
    ushort* wBhi = (ushort*)d_ws;                          // 5,308,416 ushort
    ushort* wBlo = wBhi + 5308416;
    ushort* h1hi = (ushort*)((char*)d_ws + 21233664);      // 52,428,800 ushort
    ushort* h1lo = h1hi + 52428800;
    float*  h2   = (float*)((char*)d_ws + 230948864);      // 4,718,592 f

    // post-conv2 region aliases h1 (dead after conv2)
    float* post = (float*)((char*)d_ws + 21233664);
    float* u   = post;                   // 4,718,592
    float* uT  = post + 4718592;         // 4,718,592
    float* bl  = post + 9437184;         // 5,898,240
    float* sT  = post + 15335424;        // 81,920
    float* Z   = post + 15417344;        // 5,120
    float* v   = post + 15422464;        // 81,920
    float* vT  = post + 15504384;        // 81,920
    float* dec = post + 15586304;        // 81,920
    float* r1  = post + 15668224;        // 262,144
    float* r2  = post + 15930368;        // 524,288

    int pred_off = out_size - 512;

    k_wt2<<<256, 256, 0, stream>>>(w2, wBhi, wBlo);
    k_conv1<<<2560, 256, 0, stream>>>(x, w1, b1, h1hi, h1lo);
    k_h2init<<<18432, 256, 0, stream>>>(b2, h2);
    k_conv2m<<<dim3(144, 2, 2), 256, 0, stream>>>(h1hi, h1lo, wBhi, wBlo, h2);
    k_squash<<<2304, 256, 0, stream>>>(h2, u);
    k_utr<<<dim3(144, 8), 256, 0, stream>>>(u, uT);
    // zero bl + sT + Z (contiguous: 5,985,280 floats = 5845 * 1024)
    k_zero4<<<5845, 256, 0, stream>>>(bl);

    for (int it = 0; it < 3; ++it) {
        k_s<<<dim3(144, 4), 256, 0, stream>>>(Wc, uT, bl, Z, sT, it == 0 ? 1 : 0);
        k_v<<<20, 256, 0, stream>>>(sT, v, vT, sT, Z);
        if (it < 2) k_bupd<<<dim3(144, 4), 256, 0, stream>>>(Wc, uT, vT, bl, Z);
    }

    k_pred<<<512, 256, 0, stream>>>(v, out, dec, pred_off);
    k_gemm<0><<<dim3(8, 8), 256, 0, stream>>>(dec, d1w, d1b, r1, 512, 160, 512);
    k_gemm<0><<<dim3(16, 8), 256, 0, stream>>>(r1, d2w, d2b, r2, 512, 512, 1024);
    k_gemm<1><<<dim3(13, 8), 256, 0, stream>>>(r2, d3w, d3b, out + 81920, 512, 1024, 784);
}

// Round 3
// 1596.838 us; speedup vs baseline: 2.6475x; 1.1176x over previous
//
#include <hip/hip_runtime.h>

#define CAPS_EPS 1e-8f

typedef __attribute__((ext_vector_type(8))) short short8;
typedef __attribute__((ext_vector_type(4))) float f32x4;

__device__ inline ushort bf16_rn(float f) {
    uint u = __float_as_uint(f);
    u += 0x7fff + ((u >> 16) & 1);
    return (ushort)(u >> 16);
}
__device__ inline float bf16_f(ushort h) { return __uint_as_float((uint)h << 16); }

// ============================================================
// Layouts:
//   h1hi/h1lo [512][20][20][256] bf16 (NHWC) -- conv1 out, split
//   wBhi/wBlo [256][20736] bf16, k = (ky*9+kx)*256 + c
//   h2  [512*36][256] fp32
//   u   [512][1152*8], uT [9216][512]
//   bl  [1152*10][512], Z [10][512], sT [160][512], v [512][160], vT [160][512]
// ============================================================

// ---------- w2 [256][256*81] -> wB[n][t*256+c] hi/lo ----------
__global__ __launch_bounds__(256) void k_wt2(const float* __restrict__ w2,
                                             ushort* __restrict__ wBhi,
                                             ushort* __restrict__ wBlo) {
    int n = blockIdx.x;
    int c = threadIdx.x;
    const float* src = w2 + (size_t)n * 20736 + c * 81;
    ushort* dh = wBhi + (size_t)n * 20736 + c;
    ushort* dl = wBlo + (size_t)n * 20736 + c;
    for (int t = 0; t < 81; ++t) {
        float f = src[t];
        ushort hi = bf16_rn(f);
        ushort lo = bf16_rn(f - bf16_f(hi));
        dh[t * 256] = hi;
        dl[t * 256] = lo;
    }
}

// ---------- conv1 + relu -> bf16 split NHWC ----------
__global__ __launch_bounds__(256) void k_conv1(const float* __restrict__ x,
                                               const float* __restrict__ w1,
                                               const float* __restrict__ b1,
                                               ushort* __restrict__ h1hi,
                                               ushort* __restrict__ h1lo) {
    int blk = blockIdx.x;
    int b = blk / 5, strip = blk % 5;
    int y0 = strip * 4;
    int c = threadIdx.x;
    float w[81];
#pragma unroll
    for (int k = 0; k < 81; ++k) w[k] = w1[c * 81 + k];
    float bias = b1[c];
    const float* xb = x + (size_t)b * 784;
    for (int dy = 0; dy < 4; ++dy) {
        int y = y0 + dy;
        float acc[20];
#pragma unroll
        for (int i = 0; i < 20; ++i) acc[i] = bias;
#pragma unroll
        for (int ky = 0; ky < 9; ++ky) {
            float xr[28];
            const float4* xp = reinterpret_cast<const float4*>(xb + (y + ky) * 28);
#pragma unroll
            for (int q = 0; q < 7; ++q) {
                float4 v = xp[q];
                xr[q * 4 + 0] = v.x; xr[q * 4 + 1] = v.y;
                xr[q * 4 + 2] = v.z; xr[q * 4 + 3] = v.w;
            }
#pragma unroll
            for (int kx = 0; kx < 9; ++kx) {
                float wv = w[ky * 9 + kx];
#pragma unroll
                for (int xo = 0; xo < 20; ++xo)
                    acc[xo] = fmaf(xr[xo + kx], wv, acc[xo]);
            }
        }
#pragma unroll
        for (int xo = 0; xo < 20; ++xo) {
            float a = fmaxf(acc[xo], 0.f);
            ushort hi = bf16_rn(a);
            ushort lo = bf16_rn(a - bf16_f(hi));
            size_t o = ((size_t)(b * 20 + y) * 20 + xo) * 256 + c;
            h1hi[o] = hi;
            h1lo[o] = lo;
        }
    }
}

// ---------- h2 init with bias ----------
__global__ __launch_bounds__(256) void k_h2init(const float* __restrict__ b2,
                                                float* __restrict__ h2) {
    h2[(size_t)blockIdx.x * 256 + threadIdx.x] = b2[threadIdx.x];
}

// ---------- conv2: split-bf16 MFMA implicit GEMM ----------
// C[18432][256] += A(im2col h1) * B.  128x128 tile, BK=32, K-split 4.
// 3-term split: hi*hi + hi*lo + lo*hi.
// LDS rows padded to 40 ushorts (80 B = 20 banks) -> 2-way max conflicts.
#define LPAD 40
__global__ __launch_bounds__(256) void k_conv2m(const ushort* __restrict__ h1hi,
                                                const ushort* __restrict__ h1lo,
                                                const ushort* __restrict__ wBhi,
                                                const ushort* __restrict__ wBlo,
                                                float* __restrict__ h2) {
    __shared__ ushort Ahi[128 * LPAD];
    __shared__ ushort Alo[128 * LPAD];
    __shared__ ushort Bhi[128 * LPAD];
    __shared__ ushort Blo[128 * LPAD];
    int tid = threadIdx.x;
    int m0 = blockIdx.x * 128;
    int n0 = blockIdx.y * 128;
    int kbase = blockIdx.z * 5184;          // 20736 / 4

    // staging mapping: 2 threads per row, 32B (16 bf16) each
    int mloc = tid >> 1, half = tid & 1;
    int hoff = half * 16;
    int m = m0 + mloc;
    int mb = m / 36, mp = m - mb * 36;
    int oy = mp / 6, ox = mp - oy * 6;
    const size_t abase = ((size_t)mb * 400 + oy * 40 + ox * 2) * 256;
    const size_t bbase = (size_t)(n0 + mloc) * 20736;

    // frag mapping
    int wv = tid >> 6, lane = tid & 63;
    int mhalf = (wv >> 1) * 64, nhalf = (wv & 1) * 64;
    int lrow = lane & 15, quad = lane >> 4;

    f32x4 acc[4][4];
#pragma unroll
    for (int a = 0; a < 4; ++a)
#pragma unroll
        for (int bq = 0; bq < 4; ++bq) acc[a][bq] = (f32x4){0.f, 0.f, 0.f, 0.f};

    float4 pa0, pa1, pl0, pl1, pb0, pb1, pq0, pq1;
#define LOADCHUNK(KS)                                                              \
    {                                                                              \
        int k = kbase + (KS) * 32;                                                 \
        int t = k >> 8, c = k & 255;                                               \
        int ky = t / 9, kx = t - ky * 9;                                           \
        const ushort* ap = h1hi + abase + ky * 5120 + kx * 256 + c + hoff;         \
        const ushort* al = h1lo + abase + ky * 5120 + kx * 256 + c + hoff;         \
        pa0 = *reinterpret_cast<const float4*>(ap);                                \
        pa1 = *reinterpret_cast<const float4*>(ap + 8);                            \
        pl0 = *reinterpret_cast<const float4*>(al);                                \
        pl1 = *reinterpret_cast<const float4*>(al + 8);                            \
        const ushort* bp = wBhi + bbase + k + hoff;                                \
        const ushort* bq2 = wBlo + bbase + k + hoff;                               \
        pb0 = *reinterpret_cast<const float4*>(bp);                                \
        pb1 = *reinterpret_cast<const float4*>(bp + 8);                            \
        pq0 = *reinterpret_cast<const float4*>(bq2);                               \
        pq1 = *reinterpret_cast<const float4*>(bq2 + 8);                           \
    }

    LOADCHUNK(0);
    for (int ks = 0; ks < 162; ++ks) {
        __syncthreads();
        *reinterpret_cast<float4*>(&Ahi[mloc * LPAD + hoff]) = pa0;
        *reinterpret_cast<float4*>(&Ahi[mloc * LPAD + hoff + 8]) = pa1;
        *reinterpret_cast<float4*>(&Alo[mloc * LPAD + hoff]) = pl0;
        *reinterpret_cast<float4*>(&Alo[mloc * LPAD + hoff + 8]) = pl1;
        *reinterpret_cast<float4*>(&Bhi[mloc * LPAD + hoff]) = pb0;
        *reinterpret_cast<float4*>(&Bhi[mloc * LPAD + hoff + 8]) = pb1;
        *reinterpret_cast<float4*>(&Blo[mloc * LPAD + hoff]) = pq0;
        *reinterpret_cast<float4*>(&Blo[mloc * LPAD + hoff + 8]) = pq1;
        __syncthreads();
        if (ks < 161) LOADCHUNK(ks + 1);

        short8 bh[4], blo[4];
#pragma unroll
        for (int tn = 0; tn < 4; ++tn) {
            int off = (nhalf + tn * 16 + lrow) * LPAD + quad * 8;
            bh[tn] = *reinterpret_cast<short8*>(&Bhi[off]);
            blo[tn] = *reinterpret_cast<short8*>(&Blo[off]);
        }
#pragma unroll
        for (int tm = 0; tm < 4; ++tm) {
            int off = (mhalf + tm * 16 + lrow) * LPAD + quad * 8;
            short8 ah = *reinterpret_cast<short8*>(&Ahi[off]);
            short8 al = *reinterpret_cast<short8*>(&Alo[off]);
#pragma unroll
            for (int tn = 0; tn < 4; ++tn) {
                acc[tm][tn] = __builtin_amdgcn_mfma_f32_16x16x32_bf16(ah, bh[tn], acc[tm][tn], 0, 0, 0);
                acc[tm][tn] = __builtin_amdgcn_mfma_f32_16x16x32_bf16(ah, blo[tn], acc[tm][tn], 0, 0, 0);
                acc[tm][tn] = __builtin_amdgcn_mfma_f32_16x16x32_bf16(al, bh[tn], acc[tm][tn], 0, 0, 0);
            }
        }
    }
#undef LOADCHUNK

#pragma unroll
    for (int tm = 0; tm < 4; ++tm) {
        int mrow = m0 + mhalf + tm * 16 + quad * 4;
#pragma unroll
        for (int tn = 0; tn < 4; ++tn) {
            int ncol = n0 + nhalf + tn * 16 + lrow;
#pragma unroll
            for (int r = 0; r < 4; ++r)
                atomicAdd(&h2[(size_t)(mrow + r) * 256 + ncol], acc[tm][tn][r]);
        }
    }
}

// ---------- squash over 8-dim: h2 -> u[b][i*8+n] ----------
__global__ __launch_bounds__(256) void k_squash(const float* __restrict__ h2,
                                                float* __restrict__ u) {
    int idx = blockIdx.x * 256 + threadIdx.x;
    int g = idx & 31;
    int s = (idx >> 5) % 36;
    int b = idx / 1152;
    const float* hp = h2 + ((size_t)b * 36 + s) * 256 + g;
    float val[8];
    float s2 = 0.f;
#pragma unroll
    for (int n = 0; n < 8; ++n) {
        val[n] = hp[n * 32];
        s2 = fmaf(val[n], val[n], s2);
    }
    float scale = s2 / ((1.f + s2) * sqrtf(s2 + CAPS_EPS));
    float* up = u + ((size_t)b * 1152 + g * 36 + s) * 8;
#pragma unroll
    for (int n = 0; n < 8; ++n) up[n] = val[n] * scale;
}

// ---------- u[512][9216] -> uT[9216][512] ----------
__global__ __launch_bounds__(256) void k_utr(const float* __restrict__ u,
                                             float* __restrict__ uT) {
    __shared__ float tile[64][65];
    int c0 = blockIdx.x * 64;
    int b0 = blockIdx.y * 64;
    int tid = threadIdx.x;
    int rl = tid >> 4;
    int cl = (tid & 15) * 4;
#pragma unroll
    for (int q = 0; q < 4; ++q) {
        int r = rl + q * 16;
        float4 v = *reinterpret_cast<const float4*>(u + (size_t)(b0 + r) * 9216 + c0 + cl);
        tile[r][cl + 0] = v.x; tile[r][cl + 1] = v.y;
        tile[r][cl + 2] = v.z; tile[r][cl + 3] = v.w;
    }
    __syncthreads();
    int r2 = tid >> 2;
    int c2 = (tid & 3) * 16;
#pragma unroll
    for (int q = 0; q < 4; ++q) {
        float4 v = make_float4(tile[c2 + q * 4 + 0][r2], tile[c2 + q * 4 + 1][r2],
                               tile[c2 + q * 4 + 2][r2], tile[c2 + q * 4 + 3][r2]);
        *reinterpret_cast<float4*>(uT + (size_t)(c0 + r2) * 512 + b0 + c2 + q * 4) = v;
    }
}

// ---------- zero (float4 granularity) ----------
__global__ __launch_bounds__(256) void k_zero4(float* __restrict__ p) {
    reinterpret_cast<float4*>(p)[(size_t)blockIdx.x * 256 + threadIdx.x] = make_float4(0, 0, 0, 0);
}

// ---------- s[b,j,m] = sum_i c * (W u), c from exp(bl)/Z (or uniform it0) ----------
__global__ __launch_bounds__(256) void k_s(const float* __restrict__ Wc,
                                           const float* __restrict__ uT,
                                           const float* __restrict__ bl,
                                           const float* __restrict__ Z,
                                           float* __restrict__ sT,
                                           int first) {
    __shared__ float lw[8 * 1280];
    int tid = threadIdx.x;
    int i0 = blockIdx.x * 8;
    int b = blockIdx.y * 128 + (tid & 127);
    int mh = tid >> 7;
    const float* wg = Wc + (size_t)i0 * 1280;
#pragma unroll
    for (int r = 0; r < 10; ++r) {
        int q4 = (r * 256 + tid) * 4;
        *reinterpret_cast<float4*>(&lw[q4]) = *reinterpret_cast<const float4*>(wg + q4);
    }
    __syncthreads();
    float rzs[10];
    if (!first) {
#pragma unroll
        for (int j = 0; j < 10; ++j) rzs[j] = 1.0f / Z[j * 512 + b];
    }
    float acc[80];
#pragma unroll
    for (int q = 0; q < 80; ++q) acc[q] = 0.f;
    for (int di = 0; di < 8; ++di) {
        int i = i0 + di;
        float ur[8];
#pragma unroll
        for (int n = 0; n < 8; ++n) ur[n] = uT[((size_t)i * 8 + n) * 512 + b];
#pragma unroll
        for (int j = 0; j < 10; ++j) {
            float c;
            if (first) c = (1.0f / 1152.0f);
            else c = expf(bl[((size_t)i * 10 + j) * 512 + b]) * rzs[j];
            const float* wp = &lw[((di * 10 + j) * 8) * 16 + mh * 8];
#pragma unroll
            for (int mm = 0; mm < 8; ++mm) {
                float uh = 0.f;
#pragma unroll
                for (int n = 0; n < 8; ++n) uh = fmaf(wp[n * 16 + mm], ur[n], uh);
                acc[j * 8 + mm] = fmaf(c, uh, acc[j * 8 + mm]);
            }
        }
    }
#pragma unroll
    for (int j = 0; j < 10; ++j)
#pragma unroll
        for (int mm = 0; mm < 8; ++mm)
            atomicAdd(&sT[(j * 16 + mh * 8 + mm) * 512 + b], acc[j * 8 + mm]);
}

// ---------- v = squash(s); write v, vT; zero sT and Z for next round ----------
__global__ __launch_bounds__(256) void k_v(const float* __restrict__ sT,
                                           float* __restrict__ v,
                                           float* __restrict__ vT,
                                           float* __restrict__ sTz,
                                           float* __restrict__ Z) {
    int idx = blockIdx.x * 256 + threadIdx.x;   // 5120
    int j = idx >> 9;
    int b = idx & 511;
    float sv[16];
    float s2 = 0.f;
#pragma unroll
    for (int m = 0; m < 16; ++m) {
        sv[m] = sT[(j * 16 + m) * 512 + b];
        s2 = fmaf(sv[m], sv[m], s2);
    }
    float scale = s2 / ((1.f + s2) * sqrtf(s2 + CAPS_EPS));
#pragma unroll
    for (int m = 0; m < 16; ++m) {
        float val = sv[m] * scale;
        v[(size_t)b * 160 + j * 16 + m] = val;
        vT[(j * 16 + m) * 512 + b] = val;
        sTz[(j * 16 + m) * 512 + b] = 0.f;
    }
    Z[idx] = 0.f;
}

// ---------- b_log += u . (W v); accumulate Z = sum_i exp(b_log_new) ----------
__global__ __launch_bounds__(256) void k_bupd(const float* __restrict__ Wc,
                                              const float* __restrict__ uT,
                                              const float* __restrict__ vT,
                                              float* __restrict__ bl,
                                              float* __restrict__ Z) {
    __shared__ float lw[8 * 1280];
    int tid = threadIdx.x;
    int i0 = blockIdx.x * 8;
    int b = blockIdx.y * 128 + (tid & 127);
    int ih = tid >> 7;
    const float* wg = Wc + (size_t)i0 * 1280;
#pragma unroll
    for (int r = 0; r < 10; ++r) {
        int q4 = (r * 256 + tid) * 4;
        *reinterpret_cast<float4*>(&lw[q4]) = *reinterpret_cast<const float4*>(wg + q4);
    }
    __syncthreads();
    float ur[4][8];
#pragma unroll
    for (int ii = 0; ii < 4; ++ii) {
        int i = i0 + ih * 4 + ii;
#pragma unroll
        for (int n = 0; n < 8; ++n) ur[ii][n] = uT[((size_t)i * 8 + n) * 512 + b];
    }
    for (int j = 0; j < 10; ++j) {
        float vj[16];
#pragma unroll
        for (int m = 0; m < 16; ++m) vj[m] = vT[(j * 16 + m) * 512 + b];
        float zp = 0.f;
#pragma unroll
        for (int ii = 0; ii < 4; ++ii) {
            int di = ih * 4 + ii;
            const float* wp = &lw[((di * 10 + j) * 8) * 16];
            float t = 0.f;
#pragma unroll
            for (int n = 0; n < 8; ++n) {
                float wvv = 0.f;
#pragma unroll
                for (int m = 0; m < 16; ++m) wvv = fmaf(wp[n * 16 + m], vj[m], wvv);
                t = fmaf(ur[ii][n], wvv, t);
            }
            size_t idx = ((size_t)(i0 + di) * 10 + j) * 512 + b;
            float nb = bl[idx] + t;
            bl[idx] = nb;
            zp += expf(nb);
        }
        atomicAdd(&Z[j * 512 + b], zp);
    }
}

// ---------- caps->out, pred->out, masked dec_in ----------
__global__ __launch_bounds__(256) void k_pred(const float* __restrict__ v,
                                              float* __restrict__ out,
                                              float* __restrict__ dec,
                                              int pred_off) {
    int b = blockIdx.x, t = threadIdx.x;
    __shared__ float sq[160];
    __shared__ float nrm[10];
    __shared__ int ip;
    float val = 0.f;
    if (t < 160) {
        val = v[(size_t)b * 160 + t];
        out[(size_t)b * 160 + t] = val;
        sq[t] = val * val;
    }
    __syncthreads();
    if (t < 10) {
        float s = 0.f;
#pragma unroll
        for (int k = 0; k < 16; ++k) s += sq[t * 16 + k];
        nrm[t] = s;
    }
    __syncthreads();
    if (t == 0) {
        float best = nrm[0];
        int bi = 0;
        for (int j = 1; j < 10; ++j)
            if (nrm[j] > best) { best = nrm[j]; bi = j; }
        ip = bi;
        out[(size_t)pred_off + b] = (float)bi;
    }
    __syncthreads();
    if (t < 160) dec[(size_t)b * 160 + t] = ((t >> 4) == ip) ? val : 0.f;
}

// ---------- decoder GEMM ----------
template <int ACT>
__global__ __launch_bounds__(256) void k_gemm(const float* __restrict__ A,
                                              const float* __restrict__ B,
                                              const float* __restrict__ bias,
                                              float* __restrict__ C,
                                              int M, int K, int N) {
    __shared__ float As[16 * 64];
    __shared__ float Bs[16 * 64];
    int tid = threadIdx.x;
    int m0 = blockIdx.y * 64, n0 = blockIdx.x * 64;
    int arow = tid >> 2, akq = (tid & 3) * 4;
    int brow = tid >> 4, bcol = (tid & 15) * 4;
    int ty = tid >> 4, tx = tid & 15;
    float acc[4][4];
#pragma unroll
    for (int r = 0; r < 4; ++r)
#pragma unroll
        for (int q = 0; q < 4; ++q) acc[r][q] = 0.f;
    for (int k0 = 0; k0 < K; k0 += 16) {
        float4 av = *reinterpret_cast<const float4*>(A + (size_t)(m0 + arow) * K + k0 + akq);
        float4 bv = make_float4(0, 0, 0, 0);
        if (n0 + bcol < N)
            bv = *reinterpret_cast<const float4*>(B + (size_t)(k0 + brow) * N + n0 + bcol);
        __syncthreads();
        As[(akq + 0) * 64 + arow] = av.x;
        As[(akq + 1) * 64 + arow] = av.y;
        As[(akq + 2) * 64 + arow] = av.z;
        As[(akq + 3) * 64 + arow] = av.w;
        *reinterpret_cast<float4*>(&Bs[brow * 64 + bcol]) = bv;
        __syncthreads();
#pragma unroll
        for (int kk = 0; kk < 16; ++kk) {
            float4 a4 = *reinterpret_cast<float4*>(&As[kk * 64 + ty * 4]);
            float4 b4 = *reinterpret_cast<float4*>(&Bs[kk * 64 + tx * 4]);
            float ar[4] = {a4.x, a4.y, a4.z, a4.w};
            float br[4] = {b4.x, b4.y, b4.z, b4.w};
#pragma unroll
            for (int r = 0; r < 4; ++r)
#pragma unroll
                for (int q = 0; q < 4; ++q)
                    acc[r][q] = fmaf(ar[r], br[q], acc[r][q]);
        }
    }
#pragma unroll
    for (int r = 0; r < 4; ++r) {
        int mm = m0 + ty * 4 + r;
#pragma unroll
        for (int q = 0; q < 4; ++q) {
            int nn = n0 + tx * 4 + q;
            if (nn < N) {
                float val = acc[r][q] + bias[nn];
                if (ACT == 0) val = fmaxf(val, 0.f);
                else val = 1.f / (1.f + expf(-val));
                C[(size_t)mm * N + nn] = val;
            }
        }
    }
}

extern "C" void kernel_launch(void* const* d_in, const int* in_sizes, int n_in,
                              void* d_out, int out_size, void* d_ws, size_t ws_size,
                              hipStream_t stream) {
    const float* x   = (const float*)d_in[0];
    const float* w1  = (const float*)d_in[1];
    const float* b1  = (const float*)d_in[2];
    const float* w2  = (const float*)d_in[3];
    const float* b2  = (const float*)d_in[4];
    const float* Wc  = (const float*)d_in[5];
    const float* d1w = (const float*)d_in[6];
    const float* d1b = (const float*)d_in[7];
    const float* d2w = (const float*)d_in[8];
    const float* d2b = (const float*)d_in[9];
    const float* d3w = (const float*)d_in[10];
    const float* d3b = (const float*)d_in[11];
    float* out = (float*)d_out;

    // ---- workspace (bytes): wB 21,233,664 | h1 209,715,200 | h2 18,874,368 = 249,823,232
    ushort* wBhi = (ushort*)d_ws;                          // 5,308,416 ushort
    ushort* wBlo = wBhi + 5308416;
    ushort* h1hi = (ushort*)((char*)d_ws + 21233664);      // 52,428,800 ushort
    ushort* h1lo = h1hi + 52428800;
    float*  h2   = (float*)((char*)d_ws + 230948864);      // 4,718,592 f

    // post-conv2 region aliases h1 (dead after conv2)
    float* post = (float*)((char*)d_ws + 21233664);
    float* u   = post;                   // 4,718,592
    float* uT  = post + 4718592;         // 4,718,592
    float* bl  = post + 9437184;         // 5,898,240
    float* sT  = post + 15335424;        // 81,920
    float* Z   = post + 15417344;        // 5,120
    float* v   = post + 15422464;        // 81,920
    float* vT  = post + 15504384;        // 81,920
    float* dec = post + 15586304;        // 81,920
    float* r1  = post + 15668224;        // 262,144
    float* r2  = post + 15930368;        // 524,288

    int pred_off = out_size - 512;

    k_wt2<<<256, 256, 0, stream>>>(w2, wBhi, wBlo);
    k_conv1<<<2560, 256, 0, stream>>>(x, w1, b1, h1hi, h1lo);
    k_h2init<<<18432, 256, 0, stream>>>(b2, h2);
    k_conv2m<<<dim3(144, 2, 4), 256, 0, stream>>>(h1hi, h1lo, wBhi, wBlo, h2);
    k_squash<<<2304, 256, 0, stream>>>(h2, u);
    k_utr<<<dim3(144, 8), 256, 0, stream>>>(u, uT);
    // zero bl + sT + Z (contiguous: 5,985,280 floats = 5845 * 1024)
    k_zero4<<<5845, 256, 0, stream>>>(bl);

    for (int it = 0; it < 3; ++it) {
        k_s<<<dim3(144, 4), 256, 0, stream>>>(Wc, uT, bl, Z, sT, it == 0 ? 1 : 0);
        k_v<<<20, 256, 0, stream>>>(sT, v, vT, sT, Z);
        if (it < 2) k_bupd<<<dim3(144, 4), 256, 0, stream>>>(Wc, uT, vT, bl, Z);
    }

    k_pred<<<512, 256, 0, stream>>>(v, out, dec, pred_off);
    k_gemm<0><<<dim3(8, 8), 256, 0, stream>>>(dec, d1w, d1b, r1, 512, 160, 512);
    k_gemm<0><<<dim3(16, 8), 256, 0, stream>>>(r1, d2w, d2b, r2, 512, 512, 1024);
    k_gemm<1><<<dim3(13, 8), 256, 0, stream>>>(r2, d3w, d3b, out + 81920, 512, 1024, 784);
}